// Round 1
// baseline (345.022 us; speedup 1.0000x reference)
//
#include <hip/hip_runtime.h>
#include <hip/hip_bf16.h>
#include <cstdint>
#include <cstddef>

// Problem constants (fixed shapes per reference)
#define NROWS 8192
#define DIM   1024
#define BM 128
#define BN 128
#define BK 32
#define INV_T 10.0f
#define EPS 1e-8f

typedef short  bf16x8  __attribute__((ext_vector_type(8)));
typedef float  floatx4 __attribute__((ext_vector_type(4)));

typedef __attribute__((address_space(1))) const void CGV;
typedef __attribute__((address_space(3))) void LV;

__device__ __forceinline__ void async_load16(const void* g, void* l) {
    __builtin_amdgcn_global_load_lds((CGV*)g, (LV*)l, 16, 0, 0);
}

__device__ __forceinline__ unsigned short f2bf_rne(float f) {
    union { float f; unsigned u; } c; c.f = f;
    unsigned u = c.u;
    unsigned r = (u + 0x7fffu + ((u >> 16) & 1u)) >> 16;
    return (unsigned short)r;
}

// ---------------------------------------------------------------------------
// Kernel A: fp32 -> bf16 (RNE), vectorized. 8192 blocks x 256 threads, 4 el/thread.
// ---------------------------------------------------------------------------
__global__ __launch_bounds__(256) void convert_kernel(
    const float* __restrict__ in, unsigned short* __restrict__ out)
{
    int i = (blockIdx.x * 256 + threadIdx.x) * 4;
    float4 v = *(const float4*)(in + i);
    ushort4 o;
    o.x = f2bf_rne(v.x);
    o.y = f2bf_rne(v.y);
    o.z = f2bf_rne(v.z);
    o.w = f2bf_rne(v.w);
    *(ushort4*)(out + i) = o;
}

// ---------------------------------------------------------------------------
// Kernel B: fused C = E*E^T tile -> exp(sim/T) -> row-sums (all / pos-weighted)
// m97 structure: 128x128 tile, BK=32, global_load_lds width 16, 4 waves (2x2),
// each wave 4x4 grid of 16x16x32 bf16 MFMA. Diagonal (j==i) masked in epilogue.
// ---------------------------------------------------------------------------
__global__ __launch_bounds__(256) void gemm_fused_kernel(
    const unsigned short* __restrict__ E,   // bf16 bits, row-major [NROWS][DIM]
    const int*            __restrict__ labels,
    float*                __restrict__ all_sum,
    float*                __restrict__ pos_sum)
{
    __shared__ __align__(16) unsigned short sA[BM * BK];
    __shared__ __align__(16) unsigned short sB[BN * BK];

    const int tid  = threadIdx.x;
    const int lane = tid & 63;
    const int w    = tid >> 6;
    const int wm   = w >> 1;        // wave row (0..1) -> 64 rows
    const int wn   = w & 1;         // wave col (0..1) -> 64 cols
    const int colw = lane & 15;
    const int quad = lane >> 4;

    const int rBase = blockIdx.y * BM;
    const int cBase = blockIdx.x * BN;

    // Staging: tile is 128x32 bf16 = 4096 elems = 512 x 16B. Each thread does
    // 2 loads per tile. LDS layout is flat row-major [row][32]; lane-contiguous
    // 16B chunks match global_load_lds's wave-uniform-base + lane*16 semantics.
    const int e0   = tid * 8;            // element offset, chunk 0
    const int row0 = e0 >> 5;            // /32
    const int col0 = e0 & 31;
    const int row1 = row0 + 64;          // chunk 1: e0 + 2048

    floatx4 acc[4][4];
    #pragma unroll
    for (int i = 0; i < 4; ++i)
        #pragma unroll
        for (int j = 0; j < 4; ++j)
            acc[i][j] = (floatx4)0.0f;

    // LDS fragment read offsets (elements). A-operand layout for 16x16x32:
    // A[m = lane&15][k = quad*8 + j]  (B-operand symmetric for NT gemm).
    const int aOff = (wm * 64 + colw) * BK + quad * 8;
    const int bOff = (wn * 64 + colw) * BK + quad * 8;

    const size_t gA0 = (size_t)(rBase + row0) * DIM + col0;
    const size_t gA1 = (size_t)(rBase + row1) * DIM + col0;
    const size_t gB0 = (size_t)(cBase + row0) * DIM + col0;
    const size_t gB1 = (size_t)(cBase + row1) * DIM + col0;

    for (int k0 = 0; k0 < DIM; k0 += BK) {
        __syncthreads();   // previous compute done before overwrite
        async_load16(E + gA0 + k0, &sA[e0]);
        async_load16(E + gA1 + k0, &sA[e0 + 2048]);
        async_load16(E + gB0 + k0, &sB[e0]);
        async_load16(E + gB1 + k0, &sB[e0 + 2048]);
        __syncthreads();   // vmcnt drained by compiler before barrier

        bf16x8 aF[4], bF[4];
        #pragma unroll
        for (int mt = 0; mt < 4; ++mt)
            aF[mt] = *(const bf16x8*)&sA[aOff + mt * 16 * BK];
        #pragma unroll
        for (int nt = 0; nt < 4; ++nt)
            bF[nt] = *(const bf16x8*)&sB[bOff + nt * 16 * BK];

        #pragma unroll
        for (int mt = 0; mt < 4; ++mt)
            #pragma unroll
            for (int nt = 0; nt < 4; ++nt)
                acc[mt][nt] = __builtin_amdgcn_mfma_f32_16x16x32_bf16(
                    aF[mt], bF[nt], acc[mt][nt], 0, 0, 0);
    }

    // Epilogue: exp(sim * 10), mask diagonal, reduce over columns.
    // C/D layout (16x16x32): col = lane&15, row = quad*4 + reg.
    float labf[4];
    int   gcol[4];
    #pragma unroll
    for (int nt = 0; nt < 4; ++nt) {
        gcol[nt] = cBase + wn * 64 + nt * 16 + colw;
        labf[nt] = (float)labels[gcol[nt]];
    }

    #pragma unroll
    for (int mt = 0; mt < 4; ++mt) {
        const int growBase = rBase + wm * 64 + mt * 16 + quad * 4;
        #pragma unroll
        for (int r = 0; r < 4; ++r) {
            const int grow = growBase + r;
            float sAll = 0.f, sPos = 0.f;
            #pragma unroll
            for (int nt = 0; nt < 4; ++nt) {
                float ev = __expf(acc[mt][nt][r] * INV_T);
                if (grow == gcol[nt]) ev = 0.0f;   // exclude self-similarity
                sAll += ev;
                sPos += ev * labf[nt];
            }
            // butterfly-reduce across the 16 lanes sharing this row
            #pragma unroll
            for (int off = 1; off < 16; off <<= 1) {
                sAll += __shfl_xor(sAll, off);
                sPos += __shfl_xor(sPos, off);
            }
            if (colw == 0) {
                atomicAdd(&all_sum[grow], sAll);
                atomicAdd(&pos_sum[grow], sPos);
            }
        }
    }
}

// ---------------------------------------------------------------------------
// Kernel C: loss = mean over rows with lab==1 of -log(pos/(all+eps)); 0 if n_ref<2
// ---------------------------------------------------------------------------
__global__ __launch_bounds__(256) void finalize_kernel(
    const float* __restrict__ all_sum,
    const float* __restrict__ pos_sum,
    const int*   __restrict__ labels,
    float*       __restrict__ out)
{
    __shared__ float sSum[256];
    __shared__ float sCnt[256];
    const int tid = threadIdx.x;
    float lsum = 0.f, lcnt = 0.f;
    for (int i = tid; i < NROWS; i += 256) {
        if (labels[i] > 0) {
            float p = pos_sum[i];
            float a = all_sum[i] + EPS;
            lsum += -logf(p / a);
            lcnt += 1.0f;
        }
    }
    sSum[tid] = lsum;
    sCnt[tid] = lcnt;
    __syncthreads();
    for (int s = 128; s > 0; s >>= 1) {
        if (tid < s) { sSum[tid] += sSum[tid + s]; sCnt[tid] += sCnt[tid + s]; }
        __syncthreads();
    }
    if (tid == 0) {
        float n = sCnt[0];
        out[0] = (n < 2.0f) ? 0.0f : sSum[0] / fmaxf(n, 1.0f);
    }
}

// ---------------------------------------------------------------------------
extern "C" void kernel_launch(void* const* d_in, const int* in_sizes, int n_in,
                              void* d_out, int out_size, void* d_ws, size_t ws_size,
                              hipStream_t stream) {
    const float* emb    = (const float*)d_in[0];
    const int*   labels = (const int*)d_in[1];
    float*       out    = (float*)d_out;

    // workspace layout: [bf16 E: 16 MB][all_sum: 32 KB][pos_sum: 32 KB]
    unsigned short* Ebf = (unsigned short*)d_ws;
    const size_t embBytes = (size_t)NROWS * DIM * sizeof(unsigned short);
    float* all_sum = (float*)((char*)d_ws + embBytes);
    float* pos_sum = all_sum + NROWS;

    hipMemsetAsync(all_sum, 0, 2 * NROWS * sizeof(float), stream);

    convert_kernel<<<(NROWS * DIM) / (4 * 256), 256, 0, stream>>>(emb, Ebf);

    dim3 grid(NROWS / BN, NROWS / BM);
    gemm_fused_kernel<<<grid, 256, 0, stream>>>(Ebf, labels, all_sum, pos_sum);

    finalize_kernel<<<1, 256, 0, stream>>>(all_sum, pos_sum, labels, out);
}

// Round 2
// 256.314 us; speedup vs baseline: 1.3461x; 1.3461x over previous
//
#include <hip/hip_runtime.h>
#include <hip/hip_bf16.h>
#include <cstdint>
#include <cstddef>

// Problem constants (fixed shapes per reference)
#define NROWS 8192
#define DIM   1024
#define BM 128
#define BN 128
#define BK 32
#define INV_T 10.0f
#define EPS 1e-8f

typedef short  bf16x8  __attribute__((ext_vector_type(8)));
typedef float  floatx4 __attribute__((ext_vector_type(4)));

typedef __attribute__((address_space(1))) const void CGV;
typedef __attribute__((address_space(3))) void LV;

__device__ __forceinline__ void async_load16(const void* g, void* l) {
    __builtin_amdgcn_global_load_lds((CGV*)g, (LV*)l, 16, 0, 0);
}

__device__ __forceinline__ unsigned short f2bf_rne(float f) {
    union { float f; unsigned u; } c; c.f = f;
    unsigned u = c.u;
    unsigned r = (u + 0x7fffu + ((u >> 16) & 1u)) >> 16;
    return (unsigned short)r;
}

// ---------------------------------------------------------------------------
// Kernel A: fp32 -> bf16 (RNE), vectorized.
// ---------------------------------------------------------------------------
__global__ __launch_bounds__(256) void convert_kernel(
    const float* __restrict__ in, unsigned short* __restrict__ out)
{
    int i = (blockIdx.x * 256 + threadIdx.x) * 4;
    float4 v = *(const float4*)(in + i);
    ushort4 o;
    o.x = f2bf_rne(v.x);
    o.y = f2bf_rne(v.y);
    o.z = f2bf_rne(v.z);
    o.w = f2bf_rne(v.w);
    *(ushort4*)(out + i) = o;
}

// ---------------------------------------------------------------------------
// Kernel B: symmetric-half fused GEMM.
// 1D grid over lower-triangle block pairs (bi >= bj). Off-diagonal tiles
// contribute BOTH row-reduces (rows of bi, weighted by labels of bj-cols) and
// col-reduces (rows of bj, weighted by labels of bi-rows). Diagonal tiles do
// the masked row-reduce only. LDS chunk placement is XOR-swizzled
// (c' = c ^ ((row ^ row>>2) & 3)) so quad-local ds_read_b128 lands 2-way on
// bank groups (free) instead of 8-way.
// ---------------------------------------------------------------------------
__global__ __launch_bounds__(256) void gemm_fused_kernel(
    const unsigned short* __restrict__ E,   // bf16 bits, row-major [NROWS][DIM]
    const int*            __restrict__ labels,
    float*                __restrict__ all_sum,
    float*                __restrict__ pos_sum)
{
    __shared__ __align__(16) unsigned short sA[BM * BK];
    __shared__ __align__(16) unsigned short sB[BN * BK];

    const int tid  = threadIdx.x;
    const int lane = tid & 63;
    const int w    = tid >> 6;
    const int wm   = w >> 1;        // wave row (0..1) -> 64 rows
    const int wn   = w & 1;         // wave col (0..1) -> 64 cols
    const int colw = lane & 15;
    const int quad = lane >> 4;

    // decode lower-triangle pair: t -> (bi, bj), bj <= bi
    const int t = blockIdx.x;
    int bi = (int)((sqrtf(8.0f * (float)t + 1.0f) - 1.0f) * 0.5f);
    while ((bi + 1) * (bi + 2) / 2 <= t) ++bi;
    while (bi * (bi + 1) / 2 > t) --bi;
    const int bj = t - bi * (bi + 1) / 2;

    const int rBase = bi * BM;      // rows (A tile)
    const int cBase = bj * BN;      // cols (B tile)
    const bool diag = (bi == bj);

    // Staging: 128x32 tile = 512 chunks of 16B; each thread stages chunk tid
    // and tid+256. Swizzled placement: LDS chunk k holds global chunk
    // (row=k>>2, c=(k&3)^swz(row)); swz invariant under row+=64.
    const int row0 = tid >> 2;
    const int swz0 = (row0 ^ (row0 >> 2)) & 3;
    const int col0 = (((tid & 3) ^ swz0) << 3);   // element col within 32
    const int row1 = row0 + 64;
    const int e0   = tid * 8;                     // LDS element offset, chunk 0

    floatx4 acc[4][4];
    #pragma unroll
    for (int i = 0; i < 4; ++i)
        #pragma unroll
        for (int j = 0; j < 4; ++j)
            acc[i][j] = (floatx4)0.0f;

    // Fragment read offsets (swizzled): for quad q want data chunk c=q, stored
    // at c' = q ^ swz(row). swz invariant under row += mt*16.
    const int rowA = wm * 64 + colw;
    const int swzA = (rowA ^ (rowA >> 2)) & 3;
    const int aBase = rowA * BK + ((quad ^ swzA) << 3);
    const int rowB = wn * 64 + colw;
    const int swzB = (rowB ^ (rowB >> 2)) & 3;
    const int bBase = rowB * BK + ((quad ^ swzB) << 3);

    const size_t gA0 = (size_t)(rBase + row0) * DIM + col0;
    const size_t gA1 = (size_t)(rBase + row1) * DIM + col0;
    const size_t gB0 = (size_t)(cBase + row0) * DIM + col0;
    const size_t gB1 = (size_t)(cBase + row1) * DIM + col0;

    for (int k0 = 0; k0 < DIM; k0 += BK) {
        __syncthreads();   // previous compute done before overwrite
        async_load16(E + gA0 + k0, &sA[e0]);
        async_load16(E + gA1 + k0, &sA[e0 + 2048]);
        async_load16(E + gB0 + k0, &sB[e0]);
        async_load16(E + gB1 + k0, &sB[e0 + 2048]);
        __syncthreads();   // vmcnt drained by compiler before barrier

        bf16x8 aF[4], bF[4];
        #pragma unroll
        for (int mt = 0; mt < 4; ++mt)
            aF[mt] = *(const bf16x8*)&sA[aBase + mt * 16 * BK];
        #pragma unroll
        for (int nt = 0; nt < 4; ++nt)
            bF[nt] = *(const bf16x8*)&sB[bBase + nt * 16 * BK];

        #pragma unroll
        for (int mt = 0; mt < 4; ++mt)
            #pragma unroll
            for (int nt = 0; nt < 4; ++nt)
                acc[mt][nt] = __builtin_amdgcn_mfma_f32_16x16x32_bf16(
                    aF[mt], bF[nt], acc[mt][nt], 0, 0, 0);
    }

    // Epilogue. C/D layout (16x16x32): col = lane&15, row = quad*4 + reg.
    float labc[4];
    int   gcol[4];
    #pragma unroll
    for (int nt = 0; nt < 4; ++nt) {
        gcol[nt] = cBase + wn * 64 + nt * 16 + colw;
        labc[nt] = (float)labels[gcol[nt]];
    }

    float colAll[4] = {0.f, 0.f, 0.f, 0.f};
    float colPos[4] = {0.f, 0.f, 0.f, 0.f};

    #pragma unroll
    for (int mt = 0; mt < 4; ++mt) {
        const int growBase = rBase + wm * 64 + mt * 16 + quad * 4;
        #pragma unroll
        for (int r = 0; r < 4; ++r) {
            const int grow = growBase + r;
            const float labr = (float)labels[grow];
            float sAll = 0.f, sPos = 0.f;
            #pragma unroll
            for (int nt = 0; nt < 4; ++nt) {
                float ev = __expf(acc[mt][nt][r] * INV_T);
                if (diag && grow == gcol[nt]) ev = 0.0f;  // exclude self
                sAll += ev;
                sPos += ev * labc[nt];
                colAll[nt] += ev;
                colPos[nt] += ev * labr;
            }
            // row-reduce across the 16 lanes (same quad) sharing this row
            #pragma unroll
            for (int off = 1; off < 16; off <<= 1) {
                sAll += __shfl_xor(sAll, off);
                sPos += __shfl_xor(sPos, off);
            }
            if (colw == 0) {
                atomicAdd(&all_sum[grow], sAll);
                atomicAdd(&pos_sum[grow], sPos);
            }
        }
    }

    if (!diag) {
        // col-reduce: sum across quads (lanes differing in bits 4,5)
        #pragma unroll
        for (int nt = 0; nt < 4; ++nt) {
            float a = colAll[nt], p = colPos[nt];
            a += __shfl_xor(a, 16);  p += __shfl_xor(p, 16);
            a += __shfl_xor(a, 32);  p += __shfl_xor(p, 32);
            if (quad == 0) {
                atomicAdd(&all_sum[gcol[nt]], a);
                atomicAdd(&pos_sum[gcol[nt]], p);
            }
        }
    }
}

// ---------------------------------------------------------------------------
// Kernel C: loss = mean over rows with lab==1 of -log(pos/(all+eps)); 0 if n_ref<2
// ---------------------------------------------------------------------------
__global__ __launch_bounds__(1024) void finalize_kernel(
    const float* __restrict__ all_sum,
    const float* __restrict__ pos_sum,
    const int*   __restrict__ labels,
    float*       __restrict__ out)
{
    __shared__ float sSum[1024];
    __shared__ float sCnt[1024];
    const int tid = threadIdx.x;
    float lsum = 0.f, lcnt = 0.f;
    for (int i = tid; i < NROWS; i += 1024) {
        if (labels[i] > 0) {
            float p = pos_sum[i];
            float a = all_sum[i] + EPS;
            lsum += -logf(p / a);
            lcnt += 1.0f;
        }
    }
    sSum[tid] = lsum;
    sCnt[tid] = lcnt;
    __syncthreads();
    for (int s = 512; s > 0; s >>= 1) {
        if (tid < s) { sSum[tid] += sSum[tid + s]; sCnt[tid] += sCnt[tid + s]; }
        __syncthreads();
    }
    if (tid == 0) {
        float n = sCnt[0];
        out[0] = (n < 2.0f) ? 0.0f : sSum[0] / fmaxf(n, 1.0f);
    }
}

// ---------------------------------------------------------------------------
extern "C" void kernel_launch(void* const* d_in, const int* in_sizes, int n_in,
                              void* d_out, int out_size, void* d_ws, size_t ws_size,
                              hipStream_t stream) {
    const float* emb    = (const float*)d_in[0];
    const int*   labels = (const int*)d_in[1];
    float*       out    = (float*)d_out;

    // workspace layout: [bf16 E: 16 MB][all_sum: 32 KB][pos_sum: 32 KB]
    unsigned short* Ebf = (unsigned short*)d_ws;
    const size_t embBytes = (size_t)NROWS * DIM * sizeof(unsigned short);
    float* all_sum = (float*)((char*)d_ws + embBytes);
    float* pos_sum = all_sum + NROWS;

    hipMemsetAsync(all_sum, 0, 2 * NROWS * sizeof(float), stream);

    convert_kernel<<<(NROWS * DIM) / (4 * 256), 256, 0, stream>>>(emb, Ebf);

    const int nBlocksTri = (NROWS / BM) * (NROWS / BM + 1) / 2;  // 64*65/2 = 2080
    gemm_fused_kernel<<<nBlocksTri, 256, 0, stream>>>(Ebf, labels, all_sum, pos_sum);

    finalize_kernel<<<1, 1024, 0, stream>>>(all_sum, pos_sum, labels, out);
}

// Round 3
// 217.476 us; speedup vs baseline: 1.5865x; 1.1786x over previous
//
#include <hip/hip_runtime.h>
#include <hip/hip_bf16.h>
#include <cstdint>
#include <cstddef>

// Problem constants (fixed shapes per reference)
#define NROWS 8192
#define DIM   1024
#define BM 128
#define BN 128
#define BK 64            // two 32-deep MFMA phases per barrier pair
#define INV_T 10.0f
#define EPS 1e-8f

typedef short  bf16x8  __attribute__((ext_vector_type(8)));
typedef float  floatx4 __attribute__((ext_vector_type(4)));

typedef __attribute__((address_space(1))) const void CGV;
typedef __attribute__((address_space(3))) void LV;

__device__ __forceinline__ void async_load16(const void* g, void* l) {
    __builtin_amdgcn_global_load_lds((CGV*)g, (LV*)l, 16, 0, 0);
}

__device__ __forceinline__ unsigned short f2bf_rne(float f) {
    union { float f; unsigned u; } c; c.f = f;
    unsigned u = c.u;
    unsigned r = (u + 0x7fffu + ((u >> 16) & 1u)) >> 16;
    return (unsigned short)r;
}

// ---------------------------------------------------------------------------
// Kernel A: fp32 -> bf16 (RNE), vectorized.
// ---------------------------------------------------------------------------
__global__ __launch_bounds__(256) void convert_kernel(
    const float* __restrict__ in, unsigned short* __restrict__ out)
{
    int i = (blockIdx.x * 256 + threadIdx.x) * 4;
    float4 v = *(const float4*)(in + i);
    ushort4 o;
    o.x = f2bf_rne(v.x);
    o.y = f2bf_rne(v.y);
    o.z = f2bf_rne(v.z);
    o.w = f2bf_rne(v.w);
    *(ushort4*)(out + i) = o;
}

// ---------------------------------------------------------------------------
// Kernel B: symmetric-half fused GEMM, BK=64 (16 barrier pairs instead of 32).
// LDS layout per tile: [row][8 chunks of 8 elems], chunk placement XOR-swizzled
// c' = c ^ (row&7): a quad's 16 rows (row&7 = colw&7) spread over all 8
// bank-groups, 2 lanes each -> conflict-free b128 reads.
// Off-diagonal tiles contribute row-reduces AND col-reduces (symmetry).
// ---------------------------------------------------------------------------
__global__ __launch_bounds__(256, 4) void gemm_fused_kernel(
    const unsigned short* __restrict__ E,   // bf16 bits, row-major [NROWS][DIM]
    const int*            __restrict__ labels,
    float*                __restrict__ all_sum,
    float*                __restrict__ pos_sum)
{
    __shared__ __align__(16) unsigned short sA[BM * BK];   // 16 KB
    __shared__ __align__(16) unsigned short sB[BN * BK];   // 16 KB

    const int tid  = threadIdx.x;
    const int lane = tid & 63;
    const int w    = tid >> 6;
    const int wm   = w >> 1;        // wave row (0..1) -> 64 rows
    const int wn   = w & 1;         // wave col (0..1) -> 64 cols
    const int colw = lane & 15;
    const int quad = lane >> 4;

    // decode lower-triangle pair: t -> (bi, bj), bj <= bi
    const int t = blockIdx.x;
    int bi = (int)((sqrtf(8.0f * (float)t + 1.0f) - 1.0f) * 0.5f);
    while ((bi + 1) * (bi + 2) / 2 <= t) ++bi;
    while (bi * (bi + 1) / 2 > t) --bi;
    const int bj = t - bi * (bi + 1) / 2;

    const int rBase = bi * BM;      // rows (A tile)
    const int cBase = bj * BN;      // cols (B tile)
    const bool diag = (bi == bj);

    // Staging: tile = 128x64 = 1024 chunks of 16B. Thread t stages LDS chunks
    // t, t+256, t+512, t+768 (rows t>>3 + 32j). Global column chunk is
    // swizzled: c = (t&7) ^ (row&7); row&7 invariant under +32.
    const int srow  = tid >> 3;
    const int scol  = (((tid & 7) ^ (srow & 7)) << 3);  // element col in 0..63
    const int e0    = tid * 8;                          // LDS elem offset chunk0

    floatx4 acc[4][4];
    #pragma unroll
    for (int i = 0; i < 4; ++i)
        #pragma unroll
        for (int j = 0; j < 4; ++j)
            acc[i][j] = (floatx4)0.0f;

    // Fragment read offsets: row = wm*64 + mt*16 + colw; chunk for (h,quad) is
    // (h*4+quad) ^ (colw&7). Base (mt=0,h var) precomputed per lane.
    const int swz   = colw & 7;
    const int aRow0 = (wm * 64 + colw) * BK;
    const int bRow0 = (wn * 64 + colw) * BK;

    const size_t gA0 = (size_t)(rBase + srow) * DIM + scol;
    const size_t gB0 = (size_t)(cBase + srow) * DIM + scol;
    const size_t rstep = (size_t)32 * DIM;

    for (int k0 = 0; k0 < DIM; k0 += BK) {
        __syncthreads();   // previous compute done before overwrite
        async_load16(E + gA0 + k0,             &sA[e0]);
        async_load16(E + gA0 + rstep + k0,     &sA[e0 + 2048]);
        async_load16(E + gA0 + 2 * rstep + k0, &sA[e0 + 4096]);
        async_load16(E + gA0 + 3 * rstep + k0, &sA[e0 + 6144]);
        async_load16(E + gB0 + k0,             &sB[e0]);
        async_load16(E + gB0 + rstep + k0,     &sB[e0 + 2048]);
        async_load16(E + gB0 + 2 * rstep + k0, &sB[e0 + 4096]);
        async_load16(E + gB0 + 3 * rstep + k0, &sB[e0 + 6144]);
        __syncthreads();   // vmcnt drained by compiler before barrier

        #pragma unroll
        for (int h = 0; h < 2; ++h) {
            const int cOff = (((h << 2) | quad) ^ swz) << 3;
            bf16x8 aF[4], bF[4];
            #pragma unroll
            for (int mt = 0; mt < 4; ++mt)
                aF[mt] = *(const bf16x8*)&sA[aRow0 + mt * 16 * BK + cOff];
            #pragma unroll
            for (int nt = 0; nt < 4; ++nt)
                bF[nt] = *(const bf16x8*)&sB[bRow0 + nt * 16 * BK + cOff];

            #pragma unroll
            for (int mt = 0; mt < 4; ++mt)
                #pragma unroll
                for (int nt = 0; nt < 4; ++nt)
                    acc[mt][nt] = __builtin_amdgcn_mfma_f32_16x16x32_bf16(
                        aF[mt], bF[nt], acc[mt][nt], 0, 0, 0);
        }
    }

    // Epilogue. C/D layout (16x16x32): col = lane&15, row = quad*4 + reg.
    float labc[4];
    int   gcol[4];
    #pragma unroll
    for (int nt = 0; nt < 4; ++nt) {
        gcol[nt] = cBase + wn * 64 + nt * 16 + colw;
        labc[nt] = (float)labels[gcol[nt]];
    }

    float colAll[4] = {0.f, 0.f, 0.f, 0.f};
    float colPos[4] = {0.f, 0.f, 0.f, 0.f};

    #pragma unroll
    for (int mt = 0; mt < 4; ++mt) {
        const int growBase = rBase + wm * 64 + mt * 16 + quad * 4;
        #pragma unroll
        for (int r = 0; r < 4; ++r) {
            const int grow = growBase + r;
            const float labr = (float)labels[grow];
            float sAll = 0.f, sPos = 0.f;
            #pragma unroll
            for (int nt = 0; nt < 4; ++nt) {
                float ev = __expf(acc[mt][nt][r] * INV_T);
                if (diag && grow == gcol[nt]) ev = 0.0f;  // exclude self
                sAll += ev;
                sPos += ev * labc[nt];
                colAll[nt] += ev;
                colPos[nt] += ev * labr;
            }
            // row-reduce across the 16 lanes (same quad) sharing this row
            #pragma unroll
            for (int off = 1; off < 16; off <<= 1) {
                sAll += __shfl_xor(sAll, off);
                sPos += __shfl_xor(sPos, off);
            }
            if (colw == 0) {
                atomicAdd(&all_sum[grow], sAll);
                atomicAdd(&pos_sum[grow], sPos);
            }
        }
    }

    if (!diag) {
        // col-reduce: sum across quads (lanes differing in bits 4,5)
        #pragma unroll
        for (int nt = 0; nt < 4; ++nt) {
            float a = colAll[nt], p = colPos[nt];
            a += __shfl_xor(a, 16);  p += __shfl_xor(p, 16);
            a += __shfl_xor(a, 32);  p += __shfl_xor(p, 32);
            if (quad == 0) {
                atomicAdd(&all_sum[gcol[nt]], a);
                atomicAdd(&pos_sum[gcol[nt]], p);
            }
        }
    }
}

// ---------------------------------------------------------------------------
// Kernel C: loss = mean over rows with lab==1 of -log(pos/(all+eps)); 0 if n_ref<2
// ---------------------------------------------------------------------------
__global__ __launch_bounds__(1024) void finalize_kernel(
    const float* __restrict__ all_sum,
    const float* __restrict__ pos_sum,
    const int*   __restrict__ labels,
    float*       __restrict__ out)
{
    __shared__ float sSum[1024];
    __shared__ float sCnt[1024];
    const int tid = threadIdx.x;
    float lsum = 0.f, lcnt = 0.f;
    for (int i = tid; i < NROWS; i += 1024) {
        if (labels[i] > 0) {
            float p = pos_sum[i];
            float a = all_sum[i] + EPS;
            lsum += -logf(p / a);
            lcnt += 1.0f;
        }
    }
    sSum[tid] = lsum;
    sCnt[tid] = lcnt;
    __syncthreads();
    for (int s = 512; s > 0; s >>= 1) {
        if (tid < s) { sSum[tid] += sSum[tid + s]; sCnt[tid] += sCnt[tid + s]; }
        __syncthreads();
    }
    if (tid == 0) {
        float n = sCnt[0];
        out[0] = (n < 2.0f) ? 0.0f : sSum[0] / fmaxf(n, 1.0f);
    }
}

// ---------------------------------------------------------------------------
extern "C" void kernel_launch(void* const* d_in, const int* in_sizes, int n_in,
                              void* d_out, int out_size, void* d_ws, size_t ws_size,
                              hipStream_t stream) {
    const float* emb    = (const float*)d_in[0];
    const int*   labels = (const int*)d_in[1];
    float*       out    = (float*)d_out;

    // workspace layout: [bf16 E: 16 MB][all_sum: 32 KB][pos_sum: 32 KB]
    unsigned short* Ebf = (unsigned short*)d_ws;
    const size_t embBytes = (size_t)NROWS * DIM * sizeof(unsigned short);
    float* all_sum = (float*)((char*)d_ws + embBytes);
    float* pos_sum = all_sum + NROWS;

    hipMemsetAsync(all_sum, 0, 2 * NROWS * sizeof(float), stream);

    convert_kernel<<<(NROWS * DIM) / (4 * 256), 256, 0, stream>>>(emb, Ebf);

    const int nBlocksTri = (NROWS / BM) * (NROWS / BM + 1) / 2;  // 64*65/2 = 2080
    gemm_fused_kernel<<<nBlocksTri, 256, 0, stream>>>(Ebf, labels, all_sum, pos_sum);

    finalize_kernel<<<1, 1024, 0, stream>>>(all_sum, pos_sum, labels, out);
}